// Round 10
// baseline (359.280 us; speedup 1.0000x reference)
//
#include <hip/hip_runtime.h>
#include <hip/hip_bf16.h>

#define C_DIM 256
#define NHEAD 8
#define DH 32
#define NTOK 32768   // B * Nv * hw
#define PETOK 16384  // Nv * hw
#define DFF_DIM 1024
#define LN_EPS 1e-5f

typedef unsigned int u32;
typedef unsigned short ushortT;
using frag_ab = __attribute__((ext_vector_type(8))) short;
using f32x4   = __attribute__((ext_vector_type(4))) float;

__device__ __forceinline__ float bflo(u32 u) { union { u32 i; float f; } c; c.i = u << 16; return c.f; }
__device__ __forceinline__ float bfhi(u32 u) { union { u32 i; float f; } c; c.i = u & 0xffff0000u; return c.f; }
__device__ __forceinline__ float b2f(ushortT u) { union { u32 i; float f; } c; c.i = ((u32)u) << 16; return c.f; }
__device__ __forceinline__ ushortT f2b(float f) {
    __hip_bfloat16 b = __float2bfloat16(f);
    return *reinterpret_cast<ushortT*>(&b);
}
__device__ __forceinline__ u32 packbf(float lo, float hi) {
    return (u32)f2b(lo) | ((u32)f2b(hi) << 16);
}
// async global->LDS, 16B per lane; LDS dest = wave-uniform base + lane*16
__device__ __forceinline__ void gload_lds16(const ushortT* g, ushortT* l) {
    __builtin_amdgcn_global_load_lds((const __attribute__((address_space(1))) void*)g,
                                     (__attribute__((address_space(3))) void*)l, 16, 0, 0);
}

// ---------------- fp32 -> bf16 weight converter (fused, 4 segments) ----------------
__global__ void cvt_all_kernel(const float* __restrict__ Wqkv, const float* __restrict__ Wo,
                               const float* __restrict__ W1, const float* __restrict__ W2,
                               ushortT* __restrict__ dst) {
    const int i = (blockIdx.x * 256 + threadIdx.x) * 4;   // 786432 elems total
    const float* src;
    int off;
    if (i < 196608)      { src = Wqkv; off = 0; }
    else if (i < 262144) { src = Wo;   off = 196608; }
    else if (i < 524288) { src = W1;   off = 262144; }
    else                 { src = W2;   off = 524288; }
    const float4 v = *(const float4*)&src[i - off];
    uint2 o = {packbf(v.x, v.y), packbf(v.z, v.w)};
    *(uint2*)&dst[i] = o;
}

// ---------------- rel-pos MLP -> rel[t][c] fp32 ----------------
__global__ void rel_kernel(const float* __restrict__ relW1, const float* __restrict__ relb1,
                           const float* __restrict__ relW2, const float* __restrict__ relb2,
                           float* __restrict__ rel) {
    __shared__ float hid[64];
    int t = blockIdx.x;                  // 0..255
    int ty = t >> 4, tx = t & 15;
    float cx = tx * (1.0f / 15.0f);
    float cy = ty * (1.0f / 15.0f);
    int c = threadIdx.x;
    if (c < 64) {
        float h = relW1[c * 2 + 0] * cx + relW1[c * 2 + 1] * cy + relb1[c];
        hid[c] = fmaxf(h, 0.0f);
    }
    __syncthreads();
    float acc = relb2[c];
    #pragma unroll
    for (int jj = 0; jj < 64; ++jj) acc = fmaf(hid[jj], relW2[c * 64 + jj], acc);
    rel[t * C_DIM + c] = acc;
}

// ---------------- pe (bf16): coalesced glob read + LDS transpose + rel add ----------------
__global__ __launch_bounds__(256) void pe_kernel(const float* __restrict__ glob,
                                                 const float* __restrict__ rel,
                                                 ushortT* __restrict__ peb) {
    __shared__ float tile[32][129];
    const int y = blockIdx.x;
    const int c0 = blockIdx.y * 32;
    const int i = y >> 4, ty = y & 15;
    const int tid = threadIdx.x;
    const int xl = tid & 127;
    #pragma unroll
    for (int p = 0; p < 16; ++p) {
        const int cl = p * 2 + (tid >> 7);
        tile[cl][xl] = glob[(size_t)(c0 + cl) * 16384 + y * 128 + xl];
    }
    __syncthreads();
    const int cl = tid & 31;
    #pragma unroll
    for (int p = 0; p < 16; ++p) {
        const int x = p * 8 + (tid >> 5);
        const int v = i * 8 + (x >> 4);
        const int t = ty * 16 + (x & 15);
        const float val = tile[cl][x] + rel[t * C_DIM + c0 + cl];
        peb[(size_t)(v * 256 + t) * C_DIM + c0 + cl] = f2b(val);
    }
}

// ---------------- window partition: coalesced read + transpose -> Xb (bf16) ----------------
__global__ __launch_bounds__(256) void window_kernel(const float* __restrict__ backbone,
                                                     ushortT* __restrict__ Xb) {
    __shared__ float tile[32][129];
    const int y = blockIdx.x;
    const int c0 = blockIdx.y * 32;
    const int b = blockIdx.z;
    const int i = y >> 4, ty = y & 15;
    const int tid = threadIdx.x;
    const int xl = tid & 127;
    #pragma unroll
    for (int p = 0; p < 16; ++p) {
        const int cl = p * 2 + (tid >> 7);
        tile[cl][xl] = backbone[(size_t)b * 4194304 + (size_t)(c0 + cl) * 16384 + y * 128 + xl];
    }
    __syncthreads();
    const int cl = tid & 31;
    #pragma unroll
    for (int p = 0; p < 16; ++p) {
        const int x = p * 8 + (tid >> 5);
        const int v = i * 8 + (x >> 4);
        const int t = ty * 16 + (x & 15);
        const size_t tok = (size_t)b * PETOK + v * 256 + t;
        Xb[tok * C_DIM + c0 + cl] = f2b(tile[cl][x]);
    }
}

// ---------------- scatter back + residual: transpose + coalesced write ----------------
__global__ __launch_bounds__(256) void scatter_kernel(const float* __restrict__ backbone,
                                                      const ushortT* __restrict__ X,
                                                      float* __restrict__ out) {
    __shared__ ushortT tile[128][34];
    const int y = blockIdx.x;
    const int c0 = blockIdx.y * 32;
    const int b = blockIdx.z;
    const int i = y >> 4, ty = y & 15;
    const int tid = threadIdx.x;
    const int cl = tid & 31;
    #pragma unroll
    for (int p = 0; p < 16; ++p) {
        const int x = p * 8 + (tid >> 5);
        const int v = i * 8 + (x >> 4);
        const int t = ty * 16 + (x & 15);
        const size_t tok = (size_t)b * PETOK + v * 256 + t;
        tile[x][cl] = X[tok * C_DIM + c0 + cl];
    }
    __syncthreads();
    const int xl = tid & 127;
    #pragma unroll
    for (int p = 0; p < 16; ++p) {
        const int c = c0 + p * 2 + (tid >> 7);
        const size_t gi = (size_t)b * 4194304 + (size_t)c * 16384 + y * 128 + xl;
        out[gi] = backbone[gi] + b2f(tile[xl][p * 2 + (tid >> 7)]);
    }
}

// ---------------- bf16 MFMA GEMM (m97 single-buffer) + XCD-aware tile swizzle ---------------
#define BM 128
#define BN 128
#define BK 32

template<bool FUSE_PE, bool RELU>
__global__ __launch_bounds__(256) void gemm_bf16(
        const ushortT* __restrict__ A, int lda,
        const ushortT* __restrict__ peb,
        const ushortT* __restrict__ W,
        const float* __restrict__ bias,
        ushortT* __restrict__ Cout, int ldc, int K) {
    __shared__ ushortT As[BM][BK];
    __shared__ ushortT Bs[BN][BK];
    const int nwg = gridDim.x * gridDim.y;
    const int flat = blockIdx.y * gridDim.x + blockIdx.x;
    const int cpx = nwg >> 3;
    const int swz = (flat & 7) * cpx + (flat >> 3);
    const int m0 = (swz / gridDim.x) * BM;
    const int n0 = (swz % gridDim.x) * BN;
    const int tid = threadIdx.x;
    const int lane = tid & 63;
    const int wave = tid >> 6;
    const int wm = (wave >> 1) * 64;
    const int wn = (wave & 1) * 64;
    const int fr = lane & 15;
    const int fg = lane >> 4;
    const int gRow = wave * 32 + (lane >> 2);
    const int gCol = (lane & 3) * 8;
    const int sRow = tid >> 2;
    const int sCol = (tid & 3) * 8;

    f32x4 acc[4][4];
    #pragma unroll
    for (int i = 0; i < 4; ++i)
        #pragma unroll
        for (int j = 0; j < 4; ++j)
            acc[i][j] = (f32x4){0.f, 0.f, 0.f, 0.f};

    for (int k0 = 0; k0 < K; k0 += BK) {
        if (FUSE_PE) {
            #pragma unroll
            for (int h = 0; h < 2; ++h) {
                const int row = sRow + h * 64;
                uint4 av = *(const uint4*)&A[(size_t)(m0 + row) * lda + k0 + sCol];
                const uint4 pv = *(const uint4*)&peb[(size_t)((m0 + row) & 16383) * C_DIM + k0 + sCol];
                u32* a = (u32*)&av;
                const u32* p = (const u32*)&pv;
                #pragma unroll
                for (int e = 0; e < 4; ++e)
                    a[e] = packbf(bflo(a[e]) + bflo(p[e]), bfhi(a[e]) + bfhi(p[e]));
                *(uint4*)&As[row][sCol] = av;
            }
        } else {
            gload_lds16(&A[(size_t)(m0 + gRow) * lda + k0 + gCol], &As[wave * 32][0]);
            gload_lds16(&A[(size_t)(m0 + gRow + 16) * lda + k0 + gCol], &As[wave * 32 + 16][0]);
        }
        gload_lds16(&W[(size_t)(n0 + gRow) * K + k0 + gCol], &Bs[wave * 32][0]);
        gload_lds16(&W[(size_t)(n0 + gRow + 16) * K + k0 + gCol], &Bs[wave * 32 + 16][0]);
        __syncthreads();
        frag_ab af[4], bf[4];
        #pragma unroll
        for (int i = 0; i < 4; ++i) af[i] = *(const frag_ab*)&As[wm + i * 16 + fr][fg * 8];
        #pragma unroll
        for (int j = 0; j < 4; ++j) bf[j] = *(const frag_ab*)&Bs[wn + j * 16 + fr][fg * 8];
        #pragma unroll
        for (int i = 0; i < 4; ++i)
            #pragma unroll
            for (int j = 0; j < 4; ++j)
                acc[i][j] = __builtin_amdgcn_mfma_f32_16x16x32_bf16(af[i], bf[j], acc[i][j], 0, 0, 0);
        __syncthreads();
    }
    #pragma unroll
    for (int j = 0; j < 4; ++j) {
        const float bv = bias[n0 + wn + j * 16 + fr];
        #pragma unroll
        for (int i = 0; i < 4; ++i) {
            #pragma unroll
            for (int r = 0; r < 4; ++r) {
                float v = acc[i][j][r] + bv;
                if (RELU) v = fmaxf(v, 0.0f);
                const int m = m0 + wm + i * 16 + fg * 4 + r;
                const int n = n0 + wn + j * 16 + fr;
                Cout[(size_t)m * ldc + n] = f2b(v);
            }
        }
    }
}

// ---------------- fused GEMM + residual + LayerNorm (register LN, BM=128 BN=256) -----------
// Y = A@W^T + bias (N=256); Xr = bf16(LN(Xr + Y)*g + be). 512 threads: 8 waves as 2(m)x4(n).
__global__ __launch_bounds__(512) void gemm_ln(
        const ushortT* __restrict__ A,
        const ushortT* __restrict__ W,
        const float* __restrict__ bias,
        const float* __restrict__ g, const float* __restrict__ be,
        ushortT* __restrict__ Xr, int K) {
    __shared__ ushortT As[128 * 32];          //  8 KB
    __shared__ ushortT Bs[256 * 32];          // 16 KB
    __shared__ float2 part[128][4];           //  4 KB row partials per wn-quadrant
    const int m0 = blockIdx.x * 128;
    const int tid = threadIdx.x;
    const int lane = tid & 63;
    const int wave = tid >> 6;
    const int wm = (wave >> 2) * 64;          // 0 / 64
    const int wn = (wave & 3) * 64;           // 0..192
    const int fr = lane & 15;
    const int fg = lane >> 4;
    const int gR = lane >> 2;
    const int gC = (lane & 3) * 8;

    f32x4 acc[4][4];
    #pragma unroll
    for (int i = 0; i < 4; ++i)
        #pragma unroll
        for (int j = 0; j < 4; ++j)
            acc[i][j] = (f32x4){0.f, 0.f, 0.f, 0.f};

    for (int k0 = 0; k0 < K; k0 += BK) {
        if (wave < 4) {
            gload_lds16(&A[(size_t)(m0 + wave * 32 + gR) * K + k0 + gC], &As[(wave * 32) * 32]);
            gload_lds16(&A[(size_t)(m0 + wave * 32 + 16 + gR) * K + k0 + gC], &As[(wave * 32 + 16) * 32]);
        }
        gload_lds16(&W[(size_t)(wave * 32 + gR) * K + k0 + gC], &Bs[(wave * 32) * 32]);
        gload_lds16(&W[(size_t)(wave * 32 + 16 + gR) * K + k0 + gC], &Bs[(wave * 32 + 16) * 32]);
        __syncthreads();
        frag_ab af[4], bf[4];
        #pragma unroll
        for (int i = 0; i < 4; ++i) af[i] = *(const frag_ab*)&As[(wm + i * 16 + fr) * 32 + fg * 8];
        #pragma unroll
        for (int j = 0; j < 4; ++j) bf[j] = *(const frag_ab*)&Bs[(wn + j * 16 + fr) * 32 + fg * 8];
        #pragma unroll
        for (int i = 0; i < 4; ++i)
            #pragma unroll
            for (int j = 0; j < 4; ++j)
                acc[i][j] = __builtin_amdgcn_mfma_f32_16x16x32_bf16(af[i], bf[j], acc[i][j], 0, 0, 0);
        __syncthreads();
    }
    // ---- add bias + residual X into acc (fp32 Y, pre-rounding) ----
    float bv[4], gv[4], bev[4];
    #pragma unroll
    for (int j = 0; j < 4; ++j) {
        const int n = wn + j * 16 + fr;
        bv[j] = bias[n];
        gv[j] = g[n];
        bev[j] = be[n];
    }
    #pragma unroll
    for (int i = 0; i < 4; ++i)
        #pragma unroll
        for (int r = 0; r < 4; ++r) {
            const size_t row = (size_t)(m0 + wm + i * 16 + fg * 4 + r);
            #pragma unroll
            for (int j = 0; j < 4; ++j)
                acc[i][j][r] += bv[j] + b2f(Xr[row * C_DIM + wn + j * 16 + fr]);
        }
    // ---- per-row stats: sum over j, butterfly over fr, combine over wn via LDS ----
    #pragma unroll
    for (int i = 0; i < 4; ++i)
        #pragma unroll
        for (int r = 0; r < 4; ++r) {
            float s = acc[i][0][r] + acc[i][1][r] + acc[i][2][r] + acc[i][3][r];
            float ss = acc[i][0][r] * acc[i][0][r] + acc[i][1][r] * acc[i][1][r]
                     + acc[i][2][r] * acc[i][2][r] + acc[i][3][r] * acc[i][3][r];
            #pragma unroll
            for (int off = 1; off <= 8; off <<= 1) {
                s += __shfl_xor(s, off, 64);
                ss += __shfl_xor(ss, off, 64);
            }
            if (fr == 0) {
                float2 p = {s, ss};
                part[wm + i * 16 + fg * 4 + r][wave & 3] = p;
            }
        }
    __syncthreads();
    // ---- normalize from registers, store bf16 ----
    #pragma unroll
    for (int i = 0; i < 4; ++i)
        #pragma unroll
        for (int r = 0; r < 4; ++r) {
            const int row = wm + i * 16 + fg * 4 + r;
            const float2 p0 = part[row][0];
            const float2 p1 = part[row][1];
            const float2 p2 = part[row][2];
            const float2 p3 = part[row][3];
            const float s = (p0.x + p1.x) + (p2.x + p3.x);
            const float ss = (p0.y + p1.y) + (p2.y + p3.y);
            const float mean = s * (1.0f / 256.0f);
            const float var = ss * (1.0f / 256.0f) - mean * mean;
            const float inv = rsqrtf(var + LN_EPS);
            const size_t gr = (size_t)(m0 + row);
            #pragma unroll
            for (int j = 0; j < 4; ++j) {
                const float o = (acc[i][j][r] - mean) * inv * gv[j] + bev[j];
                Xr[gr * C_DIM + wn + j * 16 + fr] = f2b(o);
            }
        }
}

// ---------------- attn pass 0: 4 waves, flash over 2 KV-chunks of 128 ----------------
#define KVC 128
__global__ __launch_bounds__(256) void attn_p0(const ushortT* __restrict__ QKb,
                                               const ushortT* __restrict__ Vb,
                                               ushortT* __restrict__ Ob) {
    __shared__ ushortT K_lds[KVC * 40];      // 10.0 KB
    __shared__ ushortT V_t[32 * 136];        //  8.5 KB
    __shared__ ushortT P_lds[4][16 * 136];   // 17.0 KB
    const int grp = blockIdx.x;              // (b*64+v)*8 + h
    const int h = grp & 7;
    const int bv = grp >> 3;
    const int base = (bv >> 6) * PETOK + (bv & 63) * 256;
    const int tid = threadIdx.x;
    const int wave = tid >> 6;
    const int lane = tid & 63;
    const int fr = lane & 15;
    const int fg = lane >> 4;
    const float scale = 0.17677669529663687f;   // 1/sqrt(32)

    frag_ab qf[4];
    size_t qtok[4];
    #pragma unroll
    for (int s = 0; s < 4; ++s) {
        qtok[s] = (size_t)(base + wave * 64 + s * 16 + fr);
        qf[s] = *(const frag_ab*)&QKb[qtok[s] * 512 + h * DH + fg * 8];
    }
    float m[4], l[4];
    f32x4 o0[4], o1[4];
    #pragma unroll
    for (int s = 0; s < 4; ++s) {
        m[s] = -1e30f; l[s] = 0.f;
        o0[s] = (f32x4){0.f, 0.f, 0.f, 0.f};
        o1[s] = (f32x4){0.f, 0.f, 0.f, 0.f};
    }

    for (int c = 0; c < 2; ++c) {
        __syncthreads();
        #pragma unroll
        for (int it = 0; it < 2; ++it) {
            const int idx = it * 256 + tid;  // 0..511
            const int row = idx >> 2, ch = idx & 3;
            const size_t tok = (size_t)(base + c * KVC + row);
            const uint4 kv = *(const uint4*)&QKb[tok * 512 + 256 + h * DH + ch * 8];
            *(uint4*)&K_lds[row * 40 + ch * 8] = kv;
            const uint4 vv = *(const uint4*)&Vb[tok * C_DIM + h * DH + ch * 8];
            const ushortT* vp = (const ushortT*)&vv;
            #pragma unroll
            for (int e = 0; e < 8; ++e) V_t[(ch * 8 + e) * 136 + row] = vp[e];
        }
        __syncthreads();
        #pragma unroll
        for (int s = 0; s < 4; ++s) {
            f32x4 sc[8];
            #pragma unroll
            for (int kt = 0; kt < 8; ++kt) {
                const frag_ab kf = *(const frag_ab*)&K_lds[(kt * 16 + fr) * 40 + fg * 8];
                sc[kt] = __builtin_amdgcn_mfma_f32_16x16x32_bf16(kf, qf[s], (f32x4){0.f, 0.f, 0.f, 0.f}, 0, 0, 0);
            }
            float mx = -1e30f;
            #pragma unroll
            for (int kt = 0; kt < 8; ++kt)
                mx = fmaxf(mx, fmaxf(fmaxf(sc[kt][0], sc[kt][1]), fmaxf(sc[kt][2], sc[kt][3])));
            mx = fmaxf(mx, __shfl_xor(mx, 16, 64));
            mx = fmaxf(mx, __shfl_xor(mx, 32, 64));
            const float nm = fmaxf(m[s], mx);
            const float corr = __expf((m[s] - nm) * scale);
            m[s] = nm;
            float lsum = 0.f;
            #pragma unroll
            for (int kt = 0; kt < 8; ++kt) {
                const float p0 = __expf((sc[kt][0] - nm) * scale);
                const float p1 = __expf((sc[kt][1] - nm) * scale);
                const float p2 = __expf((sc[kt][2] - nm) * scale);
                const float p3 = __expf((sc[kt][3] - nm) * scale);
                lsum += (p0 + p1) + (p2 + p3);
                uint2 pk;
                pk.x = packbf(p0, p1);
                pk.y = packbf(p2, p3);
                *(uint2*)&P_lds[wave][fr * 136 + kt * 16 + fg * 4] = pk;
            }
            lsum += __shfl_xor(lsum, 16, 64);
            lsum += __shfl_xor(lsum, 32, 64);
            l[s] = l[s] * corr + lsum;
            o0[s] *= corr;
            o1[s] *= corr;
            #pragma unroll
            for (int kc = 0; kc < 4; ++kc) {
                const frag_ab pf = *(const frag_ab*)&P_lds[wave][fr * 136 + kc * 32 + fg * 8];
                const frag_ab v0 = *(const frag_ab*)&V_t[fr * 136 + kc * 32 + fg * 8];
                const frag_ab v1 = *(const frag_ab*)&V_t[(16 + fr) * 136 + kc * 32 + fg * 8];
                o0[s] = __builtin_amdgcn_mfma_f32_16x16x32_bf16(v0, pf, o0[s], 0, 0, 0);
                o1[s] = __builtin_amdgcn_mfma_f32_16x16x32_bf16(v1, pf, o1[s], 0, 0, 0);
            }
        }
    }
    #pragma unroll
    for (int s = 0; s < 4; ++s) {
        const float inv = 1.0f / l[s];
        ushortT* ob = &Ob[qtok[s] * C_DIM + h * DH];
        uint2 w0, w1;
        w0.x = packbf(o0[s][0] * inv, o0[s][1] * inv);
        w0.y = packbf(o0[s][2] * inv, o0[s][3] * inv);
        w1.x = packbf(o1[s][0] * inv, o1[s][1] * inv);
        w1.y = packbf(o1[s][2] * inv, o1[s][3] * inv);
        *(uint2*)&ob[fg * 4] = w0;
        *(uint2*)&ob[16 + fg * 4] = w1;
    }
}

// ---------------- attn pass 1 (S=64): single-shot softmax per wave ----------------
__global__ __launch_bounds__(256) void attn_p1(const ushortT* __restrict__ QKb,
                                               const ushortT* __restrict__ Vb,
                                               ushortT* __restrict__ Ob) {
    __shared__ ushortT K_lds[4][64 * 40];
    __shared__ ushortT V_t[4][32 * 72];
    __shared__ ushortT P_lds[4][16 * 72];
    const int wave = threadIdx.x >> 6;
    const int lane = threadIdx.x & 63;
    const int unit = blockIdx.x * 4 + wave;
    const int h = unit & 7;
    const int g = unit >> 3;
    const int base = (g >> 8) * PETOK + (g & 255);
    const int fr = lane & 15;
    const int fg = lane >> 4;
    const float scale = 0.17677669529663687f;
    #pragma unroll
    for (int it = 0; it < 4; ++it) {
        const int idx = it * 64 + lane;
        const int row = idx >> 2, ch = idx & 3;
        const size_t tok = (size_t)(base + row * 256);
        const uint4 kv = *(const uint4*)&QKb[tok * 512 + 256 + h * DH + ch * 8];
        *(uint4*)&K_lds[wave][row * 40 + ch * 8] = kv;
        const uint4 vv = *(const uint4*)&Vb[tok * C_DIM + h * DH + ch * 8];
        const ushortT* vp = (const ushortT*)&vv;
        #pragma unroll
        for (int e = 0; e < 8; ++e) V_t[wave][(ch * 8 + e) * 72 + row] = vp[e];
    }
    #pragma unroll
    for (int s = 0; s < 4; ++s) {
        const int qq = s * 16 + fr;
        const size_t qtok = (size_t)(base + qq * 256);
        const frag_ab qf = *(const frag_ab*)&QKb[qtok * 512 + h * DH + fg * 8];
        f32x4 sc[4];
        #pragma unroll
        for (int kt = 0; kt < 4; ++kt) {
            const frag_ab kf = *(const frag_ab*)&K_lds[wave][(kt * 16 + fr) * 40 + fg * 8];
            sc[kt] = __builtin_amdgcn_mfma_f32_16x16x32_bf16(kf, qf, (f32x4){0.f, 0.f, 0.f, 0.f}, 0, 0, 0);
        }
        float mx = -1e30f;
        #pragma unroll
        for (int kt = 0; kt < 4; ++kt)
            mx = fmaxf(mx, fmaxf(fmaxf(sc[kt][0], sc[kt][1]), fmaxf(sc[kt][2], sc[kt][3])));
        mx = fmaxf(mx, __shfl_xor(mx, 16, 64));
        mx = fmaxf(mx, __shfl_xor(mx, 32, 64));
        float lsum = 0.f;
        #pragma unroll
        for (int kt = 0; kt < 4; ++kt) {
            const float p0 = __expf((sc[kt][0] - mx) * scale);
            const float p1 = __expf((sc[kt][1] - mx) * scale);
            const float p2 = __expf((sc[kt][2] - mx) * scale);
            const float p3 = __expf((sc[kt][3] - mx) * scale);
            lsum += (p0 + p1) + (p2 + p3);
            uint2 pk;
            pk.x = packbf(p0, p1);
            pk.y = packbf(p2, p3);
            *(uint2*)&P_lds[wave][fr * 72 + kt * 16 + fg * 4] = pk;
        }
        lsum += __shfl_xor(lsum, 16, 64);
        lsum += __shfl_xor(lsum, 32, 64);
        f32x4 o0 = {0.f, 0.f, 0.f, 0.f}, o1 = {0.f, 0.f, 0.f, 0.f};
        #pragma unroll
        for (int kc = 0; kc < 2; ++kc) {
            const frag_ab pf = *(const frag_ab*)&P_lds[wave][fr * 72 + kc * 32 + fg * 8];
            const frag_ab v0 = *(const frag_ab*)&V_t[wave][fr * 72 + kc * 32 + fg * 8];
            const frag_ab v1 = *(const frag_ab*)&V_t[wave][(16 + fr) * 72 + kc * 32 + fg * 8];
            o0 = __builtin_amdgcn_mfma_f32_16x16x32_bf16(v0, pf, o0, 0, 0, 0);
            o1 = __builtin_amdgcn_mfma_f32_16x16x32_bf16(v1, pf, o1, 0, 0, 0);
        }
        const float inv = 1.0f / lsum;
        ushortT* ob = &Ob[qtok * C_DIM + h * DH];
        uint2 w0, w1;
        w0.x = packbf(o0[0] * inv, o0[1] * inv);
        w0.y = packbf(o0[2] * inv, o0[3] * inv);
        w1.x = packbf(o1[0] * inv, o1[1] * inv);
        w1.y = packbf(o1[2] * inv, o1[3] * inv);
        *(uint2*)&ob[fg * 4] = w0;
        *(uint2*)&ob[16 + fg * 4] = w1;
    }
}

// ---------------- defe mask: parallel maxpool ----------------
__global__ void mask_kernel(const float* __restrict__ defe, float* __restrict__ out) {
    __shared__ float wmax[4];
    const int idx = blockIdx.x;          // 0..127
    const int b = idx >> 6;
    const int ii = (idx >> 3) & 7;
    const int jj = idx & 7;
    const int t = threadIdx.x;
    const int y = t >> 4, xx = t & 15;
    float v = defe[b * 16384 + (ii * 16 + y) * 128 + jj * 16 + xx];
    #pragma unroll
    for (int off = 32; off; off >>= 1) v = fmaxf(v, __shfl_xor(v, off, 64));
    if ((t & 63) == 0) wmax[t >> 6] = v;
    __syncthreads();
    if (t == 0) {
        float mx = fmaxf(fmaxf(wmax[0], wmax[1]), fmaxf(wmax[2], wmax[3]));
        out[8388608 + idx] = (mx > 0.0f) ? 1.0f : 0.0f;
    }
}

extern "C" void kernel_launch(void* const* d_in, const int* in_sizes, int n_in,
                              void* d_out, int out_size, void* d_ws, size_t ws_size,
                              hipStream_t stream) {
    const float* backbone = (const float*)d_in[0];
    const float* defe     = (const float*)d_in[1];
    const float* glob     = (const float*)d_in[2];
    const float* Wqkv     = (const float*)d_in[3];
    const float* bqkv     = (const float*)d_in[4];
    const float* Wo       = (const float*)d_in[5];
    const float* bo       = (const float*)d_in[6];
    const float* W1       = (const float*)d_in[7];
    const float* b1       = (const float*)d_in[8];
    const float* W2       = (const float*)d_in[9];
    const float* b2       = (const float*)d_in[10];
    const float* g1       = (const float*)d_in[11];
    const float* be1      = (const float*)d_in[12];
    const float* g2       = (const float*)d_in[13];
    const float* be2      = (const float*)d_in[14];
    const float* relW1    = (const float*)d_in[15];
    const float* relb1    = (const float*)d_in[16];
    const float* relW2    = (const float*)d_in[17];
    const float* relb2    = (const float*)d_in[18];

    // workspace layout (ushorts)
    ushortT* peb    = (ushortT*)d_ws;                       //  4,194,304
    ushortT* Wqkv_b = peb + 4194304;                        //    196,608
    ushortT* Wo_b   = Wqkv_b + 196608;                      //     65,536
    ushortT* W1_b   = Wo_b + 65536;                         //    262,144
    ushortT* W2_b   = W1_b + 262144;                        //    262,144
    ushortT* Xb     = W2_b + 262144;                        //  8,388,608
    ushortT* QKb    = Xb + 8388608;                         // 16,777,216 (Q|K, stride 512)
    ushortT* Vb     = QKb + 16777216;                       //  8,388,608
    ushortT* Ob     = Vb + 8388608;                         //  8,388,608
    ushortT* Hb     = QKb;                                  // FFN hidden aliases QK|V|O
    float*   relf   = (float*)(Ob + 8388608);               //     65,536 floats
    size_t needed = (size_t)((char*)(relf + 65536) - (char*)d_ws);
    if (ws_size < needed) return;

    cvt_all_kernel<<<768, 256, 0, stream>>>(Wqkv, Wo, W1, W2, Wqkv_b);
    rel_kernel<<<256, 256, 0, stream>>>(relW1, relb1, relW2, relb2, relf);
    pe_kernel<<<dim3(128, 8), 256, 0, stream>>>(glob, relf, peb);
    window_kernel<<<dim3(128, 8, 2), 256, 0, stream>>>(backbone, Xb);

    for (int pass = 0; pass < 2; ++pass) {
        gemm_bf16<true, false><<<dim3(512 / BN, NTOK / BM), 256, 0, stream>>>(
            Xb, C_DIM, peb, Wqkv_b, bqkv, QKb, 512, C_DIM);
        gemm_bf16<false, false><<<dim3(256 / BN, NTOK / BM), 256, 0, stream>>>(
            Xb, C_DIM, nullptr, Wqkv_b + 512 * 256, bqkv + 512, Vb, C_DIM, C_DIM);
        if (pass == 0) {
            attn_p0<<<128 * NHEAD, 256, 0, stream>>>(QKb, Vb, Ob);
        } else {
            attn_p1<<<4096 / 4, 256, 0, stream>>>(QKb, Vb, Ob);
        }
        // fused: Xb = LN(Xb + Ob@Wo^T + bo)
        gemm_ln<<<NTOK / 128, 512, 0, stream>>>(Ob, Wo_b, bo, g1, be1, Xb, C_DIM);
        gemm_bf16<false, true><<<dim3(DFF_DIM / BN, NTOK / BM), 256, 0, stream>>>(
            Xb, C_DIM, nullptr, W1_b, b1, Hb, DFF_DIM, C_DIM);
        // fused: Xb = LN(Xb + Hb@W2^T + b2)
        gemm_ln<<<NTOK / 128, 512, 0, stream>>>(Hb, W2_b, b2, g2, be2, Xb, DFF_DIM);
    }

    scatter_kernel<<<dim3(128, 8, 2), 256, 0, stream>>>(backbone, Xb, (float*)d_out);
    mask_kernel<<<128, 256, 0, stream>>>(defe, (float*)d_out);
}

// Round 11
// 358.764 us; speedup vs baseline: 1.0014x; 1.0014x over previous
//
#include <hip/hip_runtime.h>
#include <hip/hip_bf16.h>

#define C_DIM 256
#define NHEAD 8
#define DH 32
#define NTOK 32768   // B * Nv * hw
#define PETOK 16384  // Nv * hw
#define DFF_DIM 1024
#define LN_EPS 1e-5f

typedef unsigned int u32;
typedef unsigned short ushortT;
using frag_ab = __attribute__((ext_vector_type(8))) short;
using f32x4   = __attribute__((ext_vector_type(4))) float;

__device__ __forceinline__ float bflo(u32 u) { union { u32 i; float f; } c; c.i = u << 16; return c.f; }
__device__ __forceinline__ float bfhi(u32 u) { union { u32 i; float f; } c; c.i = u & 0xffff0000u; return c.f; }
__device__ __forceinline__ float b2f(ushortT u) { union { u32 i; float f; } c; c.i = ((u32)u) << 16; return c.f; }
__device__ __forceinline__ ushortT f2b(float f) {
    __hip_bfloat16 b = __float2bfloat16(f);
    return *reinterpret_cast<ushortT*>(&b);
}
__device__ __forceinline__ u32 packbf(float lo, float hi) {
    return (u32)f2b(lo) | ((u32)f2b(hi) << 16);
}
// async global->LDS, 16B per lane; LDS dest = wave-uniform base + lane*16
__device__ __forceinline__ void gload_lds16(const ushortT* g, ushortT* l) {
    __builtin_amdgcn_global_load_lds((const __attribute__((address_space(1))) void*)g,
                                     (__attribute__((address_space(3))) void*)l, 16, 0, 0);
}

// ---------------- fp32 -> bf16 weight converter (fused, 4 segments) ----------------
__global__ void cvt_all_kernel(const float* __restrict__ Wqkv, const float* __restrict__ Wo,
                               const float* __restrict__ W1, const float* __restrict__ W2,
                               ushortT* __restrict__ dst) {
    const int i = (blockIdx.x * 256 + threadIdx.x) * 4;   // 786432 elems total
    const float* src;
    int off;
    if (i < 196608)      { src = Wqkv; off = 0; }
    else if (i < 262144) { src = Wo;   off = 196608; }
    else if (i < 524288) { src = W1;   off = 262144; }
    else                 { src = W2;   off = 524288; }
    const float4 v = *(const float4*)&src[i - off];
    uint2 o = {packbf(v.x, v.y), packbf(v.z, v.w)};
    *(uint2*)&dst[i] = o;
}

// ---------------- rel-pos MLP -> rel[t][c] fp32 ----------------
__global__ void rel_kernel(const float* __restrict__ relW1, const float* __restrict__ relb1,
                           const float* __restrict__ relW2, const float* __restrict__ relb2,
                           float* __restrict__ rel) {
    __shared__ float hid[64];
    int t = blockIdx.x;                  // 0..255
    int ty = t >> 4, tx = t & 15;
    float cx = tx * (1.0f / 15.0f);
    float cy = ty * (1.0f / 15.0f);
    int c = threadIdx.x;
    if (c < 64) {
        float h = relW1[c * 2 + 0] * cx + relW1[c * 2 + 1] * cy + relb1[c];
        hid[c] = fmaxf(h, 0.0f);
    }
    __syncthreads();
    float acc = relb2[c];
    #pragma unroll
    for (int jj = 0; jj < 64; ++jj) acc = fmaf(hid[jj], relW2[c * 64 + jj], acc);
    rel[t * C_DIM + c] = acc;
}

// ---------------- pe (bf16): coalesced glob read + LDS transpose + rel add ----------------
__global__ __launch_bounds__(256) void pe_kernel(const float* __restrict__ glob,
                                                 const float* __restrict__ rel,
                                                 ushortT* __restrict__ peb) {
    __shared__ float tile[32][129];
    const int y = blockIdx.x;
    const int c0 = blockIdx.y * 32;
    const int i = y >> 4, ty = y & 15;
    const int tid = threadIdx.x;
    const int xl = tid & 127;
    #pragma unroll
    for (int p = 0; p < 16; ++p) {
        const int cl = p * 2 + (tid >> 7);
        tile[cl][xl] = glob[(size_t)(c0 + cl) * 16384 + y * 128 + xl];
    }
    __syncthreads();
    const int cl = tid & 31;
    #pragma unroll
    for (int p = 0; p < 16; ++p) {
        const int x = p * 8 + (tid >> 5);
        const int v = i * 8 + (x >> 4);
        const int t = ty * 16 + (x & 15);
        const float val = tile[cl][x] + rel[t * C_DIM + c0 + cl];
        peb[(size_t)(v * 256 + t) * C_DIM + c0 + cl] = f2b(val);
    }
}

// ---------------- window partition: coalesced read + transpose -> Xb (bf16) ----------------
__global__ __launch_bounds__(256) void window_kernel(const float* __restrict__ backbone,
                                                     ushortT* __restrict__ Xb) {
    __shared__ float tile[32][129];
    const int y = blockIdx.x;
    const int c0 = blockIdx.y * 32;
    const int b = blockIdx.z;
    const int i = y >> 4, ty = y & 15;
    const int tid = threadIdx.x;
    const int xl = tid & 127;
    #pragma unroll
    for (int p = 0; p < 16; ++p) {
        const int cl = p * 2 + (tid >> 7);
        tile[cl][xl] = backbone[(size_t)b * 4194304 + (size_t)(c0 + cl) * 16384 + y * 128 + xl];
    }
    __syncthreads();
    const int cl = tid & 31;
    #pragma unroll
    for (int p = 0; p < 16; ++p) {
        const int x = p * 8 + (tid >> 5);
        const int v = i * 8 + (x >> 4);
        const int t = ty * 16 + (x & 15);
        const size_t tok = (size_t)b * PETOK + v * 256 + t;
        Xb[tok * C_DIM + c0 + cl] = f2b(tile[cl][x]);
    }
}

// ---------------- scatter back + residual: transpose + coalesced write ----------------
__global__ __launch_bounds__(256) void scatter_kernel(const float* __restrict__ backbone,
                                                      const ushortT* __restrict__ X,
                                                      float* __restrict__ out) {
    __shared__ ushortT tile[128][34];
    const int y = blockIdx.x;
    const int c0 = blockIdx.y * 32;
    const int b = blockIdx.z;
    const int i = y >> 4, ty = y & 15;
    const int tid = threadIdx.x;
    const int cl = tid & 31;
    #pragma unroll
    for (int p = 0; p < 16; ++p) {
        const int x = p * 8 + (tid >> 5);
        const int v = i * 8 + (x >> 4);
        const int t = ty * 16 + (x & 15);
        const size_t tok = (size_t)b * PETOK + v * 256 + t;
        tile[x][cl] = X[tok * C_DIM + c0 + cl];
    }
    __syncthreads();
    const int xl = tid & 127;
    #pragma unroll
    for (int p = 0; p < 16; ++p) {
        const int c = c0 + p * 2 + (tid >> 7);
        const size_t gi = (size_t)b * 4194304 + (size_t)c * 16384 + y * 128 + xl;
        out[gi] = backbone[gi] + b2f(tile[xl][p * 2 + (tid >> 7)]);
    }
}

// ---------------- bf16 MFMA GEMM (m97 single-buffer) + XCD-aware tile swizzle ---------------
#define BM 128
#define BN 128
#define BK 32

template<bool FUSE_PE, bool RELU>
__global__ __launch_bounds__(256) void gemm_bf16(
        const ushortT* __restrict__ A, int lda,
        const ushortT* __restrict__ peb,
        const ushortT* __restrict__ W,
        const float* __restrict__ bias,
        ushortT* __restrict__ Cout, int ldc, int K) {
    __shared__ ushortT As[BM][BK];
    __shared__ ushortT Bs[BN][BK];
    const int nwg = gridDim.x * gridDim.y;
    const int flat = blockIdx.y * gridDim.x + blockIdx.x;
    const int cpx = nwg >> 3;
    const int swz = (flat & 7) * cpx + (flat >> 3);
    const int m0 = (swz / gridDim.x) * BM;
    const int n0 = (swz % gridDim.x) * BN;
    const int tid = threadIdx.x;
    const int lane = tid & 63;
    const int wave = tid >> 6;
    const int wm = (wave >> 1) * 64;
    const int wn = (wave & 1) * 64;
    const int fr = lane & 15;
    const int fg = lane >> 4;
    const int gRow = wave * 32 + (lane >> 2);
    const int gCol = (lane & 3) * 8;
    const int sRow = tid >> 2;
    const int sCol = (tid & 3) * 8;

    f32x4 acc[4][4];
    #pragma unroll
    for (int i = 0; i < 4; ++i)
        #pragma unroll
        for (int j = 0; j < 4; ++j)
            acc[i][j] = (f32x4){0.f, 0.f, 0.f, 0.f};

    for (int k0 = 0; k0 < K; k0 += BK) {
        if (FUSE_PE) {
            #pragma unroll
            for (int h = 0; h < 2; ++h) {
                const int row = sRow + h * 64;
                uint4 av = *(const uint4*)&A[(size_t)(m0 + row) * lda + k0 + sCol];
                const uint4 pv = *(const uint4*)&peb[(size_t)((m0 + row) & 16383) * C_DIM + k0 + sCol];
                u32* a = (u32*)&av;
                const u32* p = (const u32*)&pv;
                #pragma unroll
                for (int e = 0; e < 4; ++e)
                    a[e] = packbf(bflo(a[e]) + bflo(p[e]), bfhi(a[e]) + bfhi(p[e]));
                *(uint4*)&As[row][sCol] = av;
            }
        } else {
            gload_lds16(&A[(size_t)(m0 + gRow) * lda + k0 + gCol], &As[wave * 32][0]);
            gload_lds16(&A[(size_t)(m0 + gRow + 16) * lda + k0 + gCol], &As[wave * 32 + 16][0]);
        }
        gload_lds16(&W[(size_t)(n0 + gRow) * K + k0 + gCol], &Bs[wave * 32][0]);
        gload_lds16(&W[(size_t)(n0 + gRow + 16) * K + k0 + gCol], &Bs[wave * 32 + 16][0]);
        __syncthreads();
        frag_ab af[4], bf[4];
        #pragma unroll
        for (int i = 0; i < 4; ++i) af[i] = *(const frag_ab*)&As[wm + i * 16 + fr][fg * 8];
        #pragma unroll
        for (int j = 0; j < 4; ++j) bf[j] = *(const frag_ab*)&Bs[wn + j * 16 + fr][fg * 8];
        #pragma unroll
        for (int i = 0; i < 4; ++i)
            #pragma unroll
            for (int j = 0; j < 4; ++j)
                acc[i][j] = __builtin_amdgcn_mfma_f32_16x16x32_bf16(af[i], bf[j], acc[i][j], 0, 0, 0);
        __syncthreads();
    }
    #pragma unroll
    for (int j = 0; j < 4; ++j) {
        const float bv = bias[n0 + wn + j * 16 + fr];
        #pragma unroll
        for (int i = 0; i < 4; ++i) {
            #pragma unroll
            for (int r = 0; r < 4; ++r) {
                float v = acc[i][j][r] + bv;
                if (RELU) v = fmaxf(v, 0.0f);
                const int m = m0 + wm + i * 16 + fg * 4 + r;
                const int n = n0 + wn + j * 16 + fr;
                Cout[(size_t)m * ldc + n] = f2b(v);
            }
        }
    }
}

// ---------------- attn pass 0: 2-wave blocks (128 queries), flash over 2 KV-chunks ----------
#define KVC 128
__global__ __launch_bounds__(128) void attn_p0(const ushortT* __restrict__ QKb,
                                               const ushortT* __restrict__ Vb,
                                               ushortT* __restrict__ Ob) {
    __shared__ ushortT K_lds[KVC * 40];      // 10.0 KB
    __shared__ ushortT V_t[32 * 136];        //  8.5 KB
    __shared__ ushortT P_lds[2][16 * 136];   //  8.5 KB
    const int half = blockIdx.x & 1;
    const int grp = blockIdx.x >> 1;         // (b*64+v)*8 + h
    const int h = grp & 7;
    const int bv = grp >> 3;
    const int base = (bv >> 6) * PETOK + (bv & 63) * 256;
    const int tid = threadIdx.x;             // 0..127
    const int wave = tid >> 6;
    const int lane = tid & 63;
    const int fr = lane & 15;
    const int fg = lane >> 4;
    const float scale = 0.17677669529663687f;   // 1/sqrt(32)

    frag_ab qf[4];
    size_t qtok[4];
    #pragma unroll
    for (int s = 0; s < 4; ++s) {
        qtok[s] = (size_t)(base + half * 128 + wave * 64 + s * 16 + fr);
        qf[s] = *(const frag_ab*)&QKb[qtok[s] * 512 + h * DH + fg * 8];
    }
    float m[4], l[4];
    f32x4 o0[4], o1[4];
    #pragma unroll
    for (int s = 0; s < 4; ++s) {
        m[s] = -1e30f; l[s] = 0.f;
        o0[s] = (f32x4){0.f, 0.f, 0.f, 0.f};
        o1[s] = (f32x4){0.f, 0.f, 0.f, 0.f};
    }

    for (int c = 0; c < 2; ++c) {
        __syncthreads();
        #pragma unroll
        for (int it = 0; it < 4; ++it) {
            const int idx = it * 128 + tid;  // 0..511
            const int row = idx >> 2, ch = idx & 3;
            const size_t tok = (size_t)(base + c * KVC + row);
            const uint4 kv = *(const uint4*)&QKb[tok * 512 + 256 + h * DH + ch * 8];
            *(uint4*)&K_lds[row * 40 + ch * 8] = kv;
            const uint4 vv = *(const uint4*)&Vb[tok * C_DIM + h * DH + ch * 8];
            const ushortT* vp = (const ushortT*)&vv;
            #pragma unroll
            for (int e = 0; e < 8; ++e) V_t[(ch * 8 + e) * 136 + row] = vp[e];
        }
        __syncthreads();
        #pragma unroll
        for (int s = 0; s < 4; ++s) {
            f32x4 sc[8];
            #pragma unroll
            for (int kt = 0; kt < 8; ++kt) {
                const frag_ab kf = *(const frag_ab*)&K_lds[(kt * 16 + fr) * 40 + fg * 8];
                sc[kt] = __builtin_amdgcn_mfma_f32_16x16x32_bf16(kf, qf[s], (f32x4){0.f, 0.f, 0.f, 0.f}, 0, 0, 0);
            }
            float mx = -1e30f;
            #pragma unroll
            for (int kt = 0; kt < 8; ++kt)
                mx = fmaxf(mx, fmaxf(fmaxf(sc[kt][0], sc[kt][1]), fmaxf(sc[kt][2], sc[kt][3])));
            mx = fmaxf(mx, __shfl_xor(mx, 16, 64));
            mx = fmaxf(mx, __shfl_xor(mx, 32, 64));
            const float nm = fmaxf(m[s], mx);
            const float corr = __expf((m[s] - nm) * scale);
            m[s] = nm;
            float lsum = 0.f;
            #pragma unroll
            for (int kt = 0; kt < 8; ++kt) {
                const float p0 = __expf((sc[kt][0] - nm) * scale);
                const float p1 = __expf((sc[kt][1] - nm) * scale);
                const float p2 = __expf((sc[kt][2] - nm) * scale);
                const float p3 = __expf((sc[kt][3] - nm) * scale);
                lsum += (p0 + p1) + (p2 + p3);
                uint2 pk;
                pk.x = packbf(p0, p1);
                pk.y = packbf(p2, p3);
                *(uint2*)&P_lds[wave][fr * 136 + kt * 16 + fg * 4] = pk;
            }
            lsum += __shfl_xor(lsum, 16, 64);
            lsum += __shfl_xor(lsum, 32, 64);
            l[s] = l[s] * corr + lsum;
            o0[s] *= corr;
            o1[s] *= corr;
            #pragma unroll
            for (int kc = 0; kc < 4; ++kc) {
                const frag_ab pf = *(const frag_ab*)&P_lds[wave][fr * 136 + kc * 32 + fg * 8];
                const frag_ab v0 = *(const frag_ab*)&V_t[fr * 136 + kc * 32 + fg * 8];
                const frag_ab v1 = *(const frag_ab*)&V_t[(16 + fr) * 136 + kc * 32 + fg * 8];
                o0[s] = __builtin_amdgcn_mfma_f32_16x16x32_bf16(v0, pf, o0[s], 0, 0, 0);
                o1[s] = __builtin_amdgcn_mfma_f32_16x16x32_bf16(v1, pf, o1[s], 0, 0, 0);
            }
        }
    }
    #pragma unroll
    for (int s = 0; s < 4; ++s) {
        const float inv = 1.0f / l[s];
        ushortT* ob = &Ob[qtok[s] * C_DIM + h * DH];
        uint2 w0, w1;
        w0.x = packbf(o0[s][0] * inv, o0[s][1] * inv);
        w0.y = packbf(o0[s][2] * inv, o0[s][3] * inv);
        w1.x = packbf(o1[s][0] * inv, o1[s][1] * inv);
        w1.y = packbf(o1[s][2] * inv, o1[s][3] * inv);
        *(uint2*)&ob[fg * 4] = w0;
        *(uint2*)&ob[16 + fg * 4] = w1;
    }
}

// ---------------- attn pass 1 (S=64): single-shot softmax per wave ----------------
__global__ __launch_bounds__(256) void attn_p1(const ushortT* __restrict__ QKb,
                                               const ushortT* __restrict__ Vb,
                                               ushortT* __restrict__ Ob) {
    __shared__ ushortT K_lds[4][64 * 40];
    __shared__ ushortT V_t[4][32 * 72];
    __shared__ ushortT P_lds[4][16 * 72];
    const int wave = threadIdx.x >> 6;
    const int lane = threadIdx.x & 63;
    const int unit = blockIdx.x * 4 + wave;
    const int h = unit & 7;
    const int g = unit >> 3;
    const int base = (g >> 8) * PETOK + (g & 255);
    const int fr = lane & 15;
    const int fg = lane >> 4;
    const float scale = 0.17677669529663687f;
    #pragma unroll
    for (int it = 0; it < 4; ++it) {
        const int idx = it * 64 + lane;
        const int row = idx >> 2, ch = idx & 3;
        const size_t tok = (size_t)(base + row * 256);
        const uint4 kv = *(const uint4*)&QKb[tok * 512 + 256 + h * DH + ch * 8];
        *(uint4*)&K_lds[wave][row * 40 + ch * 8] = kv;
        const uint4 vv = *(const uint4*)&Vb[tok * C_DIM + h * DH + ch * 8];
        const ushortT* vp = (const ushortT*)&vv;
        #pragma unroll
        for (int e = 0; e < 8; ++e) V_t[wave][(ch * 8 + e) * 72 + row] = vp[e];
    }
    #pragma unroll
    for (int s = 0; s < 4; ++s) {
        const int qq = s * 16 + fr;
        const size_t qtok = (size_t)(base + qq * 256);
        const frag_ab qf = *(const frag_ab*)&QKb[qtok * 512 + h * DH + fg * 8];
        f32x4 sc[4];
        #pragma unroll
        for (int kt = 0; kt < 4; ++kt) {
            const frag_ab kf = *(const frag_ab*)&K_lds[wave][(kt * 16 + fr) * 40 + fg * 8];
            sc[kt] = __builtin_amdgcn_mfma_f32_16x16x32_bf16(kf, qf, (f32x4){0.f, 0.f, 0.f, 0.f}, 0, 0, 0);
        }
        float mx = -1e30f;
        #pragma unroll
        for (int kt = 0; kt < 4; ++kt)
            mx = fmaxf(mx, fmaxf(fmaxf(sc[kt][0], sc[kt][1]), fmaxf(sc[kt][2], sc[kt][3])));
        mx = fmaxf(mx, __shfl_xor(mx, 16, 64));
        mx = fmaxf(mx, __shfl_xor(mx, 32, 64));
        float lsum = 0.f;
        #pragma unroll
        for (int kt = 0; kt < 4; ++kt) {
            const float p0 = __expf((sc[kt][0] - mx) * scale);
            const float p1 = __expf((sc[kt][1] - mx) * scale);
            const float p2 = __expf((sc[kt][2] - mx) * scale);
            const float p3 = __expf((sc[kt][3] - mx) * scale);
            lsum += (p0 + p1) + (p2 + p3);
            uint2 pk;
            pk.x = packbf(p0, p1);
            pk.y = packbf(p2, p3);
            *(uint2*)&P_lds[wave][fr * 72 + kt * 16 + fg * 4] = pk;
        }
        lsum += __shfl_xor(lsum, 16, 64);
        lsum += __shfl_xor(lsum, 32, 64);
        f32x4 o0 = {0.f, 0.f, 0.f, 0.f}, o1 = {0.f, 0.f, 0.f, 0.f};
        #pragma unroll
        for (int kc = 0; kc < 2; ++kc) {
            const frag_ab pf = *(const frag_ab*)&P_lds[wave][fr * 72 + kc * 32 + fg * 8];
            const frag_ab v0 = *(const frag_ab*)&V_t[wave][fr * 72 + kc * 32 + fg * 8];
            const frag_ab v1 = *(const frag_ab*)&V_t[wave][(16 + fr) * 72 + kc * 32 + fg * 8];
            o0 = __builtin_amdgcn_mfma_f32_16x16x32_bf16(v0, pf, o0, 0, 0, 0);
            o1 = __builtin_amdgcn_mfma_f32_16x16x32_bf16(v1, pf, o1, 0, 0, 0);
        }
        const float inv = 1.0f / lsum;
        ushortT* ob = &Ob[qtok * C_DIM + h * DH];
        uint2 w0, w1;
        w0.x = packbf(o0[0] * inv, o0[1] * inv);
        w0.y = packbf(o0[2] * inv, o0[3] * inv);
        w1.x = packbf(o1[0] * inv, o1[1] * inv);
        w1.y = packbf(o1[2] * inv, o1[3] * inv);
        *(uint2*)&ob[fg * 4] = w0;
        *(uint2*)&ob[16 + fg * 4] = w1;
    }
}

// ---------------- residual + LayerNorm (bf16 stream) ----------------
__global__ __launch_bounds__(256) void ln_kernel(ushortT* __restrict__ X, const ushortT* __restrict__ Y,
                                                 const float* __restrict__ g, const float* __restrict__ be) {
    int tok = blockIdx.x * 4 + (threadIdx.x >> 6);
    int lane = threadIdx.x & 63;
    const uint2 xu = *(const uint2*)&X[(size_t)tok * C_DIM + lane * 4];
    const uint2 yu = *(const uint2*)&Y[(size_t)tok * C_DIM + lane * 4];
    float v0 = bflo(xu.x) + bflo(yu.x), v1 = bfhi(xu.x) + bfhi(yu.x);
    float v2 = bflo(xu.y) + bflo(yu.y), v3 = bfhi(xu.y) + bfhi(yu.y);
    float s = v0 + v1 + v2 + v3;
    float ss = v0 * v0 + v1 * v1 + v2 * v2 + v3 * v3;
    #pragma unroll
    for (int off = 32; off; off >>= 1) {
        s += __shfl_xor(s, off, 64);
        ss += __shfl_xor(ss, off, 64);
    }
    float mean = s * (1.0f / 256.0f);
    float var = ss * (1.0f / 256.0f) - mean * mean;
    float inv = rsqrtf(var + LN_EPS);
    const float4 gv = *(const float4*)&g[lane * 4];
    const float4 bv = *(const float4*)&be[lane * 4];
    float o0 = (v0 - mean) * inv * gv.x + bv.x;
    float o1 = (v1 - mean) * inv * gv.y + bv.y;
    float o2 = (v2 - mean) * inv * gv.z + bv.z;
    float o3 = (v3 - mean) * inv * gv.w + bv.w;
    uint2 ob = {packbf(o0, o1), packbf(o2, o3)};
    *(uint2*)&X[(size_t)tok * C_DIM + lane * 4] = ob;
}

// ---------------- defe mask: parallel maxpool ----------------
__global__ void mask_kernel(const float* __restrict__ defe, float* __restrict__ out) {
    __shared__ float wmax[4];
    const int idx = blockIdx.x;          // 0..127
    const int b = idx >> 6;
    const int ii = (idx >> 3) & 7;
    const int jj = idx & 7;
    const int t = threadIdx.x;
    const int y = t >> 4, xx = t & 15;
    float v = defe[b * 16384 + (ii * 16 + y) * 128 + jj * 16 + xx];
    #pragma unroll
    for (int off = 32; off; off >>= 1) v = fmaxf(v, __shfl_xor(v, off, 64));
    if ((t & 63) == 0) wmax[t >> 6] = v;
    __syncthreads();
    if (t == 0) {
        float mx = fmaxf(fmaxf(wmax[0], wmax[1]), fmaxf(wmax[2], wmax[3]));
        out[8388608 + idx] = (mx > 0.0f) ? 1.0f : 0.0f;
    }
}

extern "C" void kernel_launch(void* const* d_in, const int* in_sizes, int n_in,
                              void* d_out, int out_size, void* d_ws, size_t ws_size,
                              hipStream_t stream) {
    const float* backbone = (const float*)d_in[0];
    const float* defe     = (const float*)d_in[1];
    const float* glob     = (const float*)d_in[2];
    const float* Wqkv     = (const float*)d_in[3];
    const float* bqkv     = (const float*)d_in[4];
    const float* Wo       = (const float*)d_in[5];
    const float* bo       = (const float*)d_in[6];
    const float* W1       = (const float*)d_in[7];
    const float* b1       = (const float*)d_in[8];
    const float* W2       = (const float*)d_in[9];
    const float* b2       = (const float*)d_in[10];
    const float* g1       = (const float*)d_in[11];
    const float* be1      = (const float*)d_in[12];
    const float* g2       = (const float*)d_in[13];
    const float* be2      = (const float*)d_in[14];
    const float* relW1    = (const float*)d_in[15];
    const float* relb1    = (const float*)d_in[16];
    const float* relW2    = (const float*)d_in[17];
    const float* relb2    = (const float*)d_in[18];

    // workspace layout (ushorts)
    ushortT* peb    = (ushortT*)d_ws;                       //  4,194,304
    ushortT* Wqkv_b = peb + 4194304;                        //    196,608
    ushortT* Wo_b   = Wqkv_b + 196608;                      //     65,536
    ushortT* W1_b   = Wo_b + 65536;                         //    262,144
    ushortT* W2_b   = W1_b + 262144;                        //    262,144
    ushortT* Xb     = W2_b + 262144;                        //  8,388,608
    ushortT* QKb    = Xb + 8388608;                         // 16,777,216 (Q|K, stride 512)
    ushortT* Vb     = QKb + 16777216;                       //  8,388,608
    ushortT* Ob     = Vb + 8388608;                         //  8,388,608
    ushortT* Hb     = QKb;                                  // FFN hidden aliases QK|V|O
    ushortT* Yb     = Ob + 8388608;                         //  8,388,608
    float*   relf   = (float*)(Yb + 8388608);               //     65,536 floats
    size_t needed = (size_t)((char*)(relf + 65536) - (char*)d_ws);
    if (ws_size < needed) return;

    cvt_all_kernel<<<768, 256, 0, stream>>>(Wqkv, Wo, W1, W2, Wqkv_b);
    rel_kernel<<<256, 256, 0, stream>>>(relW1, relb1, relW2, relb2, relf);
    pe_kernel<<<dim3(128, 8), 256, 0, stream>>>(glob, relf, peb);
    window_kernel<<<dim3(128, 8, 2), 256, 0, stream>>>(backbone, Xb);

    for (int pass = 0; pass < 2; ++pass) {
        gemm_bf16<true, false><<<dim3(512 / BN, NTOK / BM), 256, 0, stream>>>(
            Xb, C_DIM, peb, Wqkv_b, bqkv, QKb, 512, C_DIM);
        gemm_bf16<false, false><<<dim3(256 / BN, NTOK / BM), 256, 0, stream>>>(
            Xb, C_DIM, nullptr, Wqkv_b + 512 * 256, bqkv + 512, Vb, C_DIM, C_DIM);
        if (pass == 0) {
            attn_p0<<<2048, 128, 0, stream>>>(QKb, Vb, Ob);
        } else {
            attn_p1<<<4096 / 4, 256, 0, stream>>>(QKb, Vb, Ob);
        }
        gemm_bf16<false, false><<<dim3(256 / BN, NTOK / BM), 256, 0, stream>>>(
            Ob, C_DIM, nullptr, Wo_b, bo, Yb, C_DIM, C_DIM);
        ln_kernel<<<NTOK / 4, 256, 0, stream>>>(Xb, Yb, g1, be1);
        gemm_bf16<false, true><<<dim3(DFF_DIM / BN, NTOK / BM), 256, 0, stream>>>(
            Xb, C_DIM, nullptr, W1_b, b1, Hb, DFF_DIM, C_DIM);
        gemm_bf16<false, false><<<dim3(256 / BN, NTOK / BM), 256, 0, stream>>>(
            Hb, DFF_DIM, nullptr, W2_b, b2, Yb, C_DIM, DFF_DIM);
        ln_kernel<<<NTOK / 4, 256, 0, stream>>>(Xb, Yb, g2, be2);
    }

    scatter_kernel<<<dim3(128, 8, 2), 256, 0, stream>>>(backbone, Xb, (float*)d_out);
    mask_kernel<<<128, 256, 0, stream>>>(defe, (float*)d_out);
}

// Round 12
// 335.819 us; speedup vs baseline: 1.0699x; 1.0683x over previous
//
#include <hip/hip_runtime.h>
#include <hip/hip_bf16.h>

#define C_DIM 256
#define NHEAD 8
#define DH 32
#define NTOK 32768   // B * Nv * hw
#define PETOK 16384  // Nv * hw
#define DFF_DIM 1024
#define LN_EPS 1e-5f

typedef unsigned int u32;
typedef unsigned short ushortT;
using frag_ab = __attribute__((ext_vector_type(8))) short;
using f32x4   = __attribute__((ext_vector_type(4))) float;

__device__ __forceinline__ float bflo(u32 u) { union { u32 i; float f; } c; c.i = u << 16; return c.f; }
__device__ __forceinline__ float bfhi(u32 u) { union { u32 i; float f; } c; c.i = u & 0xffff0000u; return c.f; }
__device__ __forceinline__ float b2f(ushortT u) { union { u32 i; float f; } c; c.i = ((u32)u) << 16; return c.f; }
__device__ __forceinline__ ushortT f2b(float f) {
    __hip_bfloat16 b = __float2bfloat16(f);
    return *reinterpret_cast<ushortT*>(&b);
}
__device__ __forceinline__ u32 packbf(float lo, float hi) {
    return (u32)f2b(lo) | ((u32)f2b(hi) << 16);
}
// async global->LDS, 16B per lane; LDS dest = wave-uniform base + lane*16
__device__ __forceinline__ void gload_lds16(const ushortT* g, ushortT* l) {
    __builtin_amdgcn_global_load_lds((const __attribute__((address_space(1))) void*)g,
                                     (__attribute__((address_space(3))) void*)l, 16, 0, 0);
}

// ---------------- fp32 -> bf16 weight converter (fused, 4 segments) ----------------
__global__ void cvt_all_kernel(const float* __restrict__ Wqkv, const float* __restrict__ Wo,
                               const float* __restrict__ W1, const float* __restrict__ W2,
                               ushortT* __restrict__ dst) {
    const int i = (blockIdx.x * 256 + threadIdx.x) * 4;   // 786432 elems total
    const float* src;
    int off;
    if (i < 196608)      { src = Wqkv; off = 0; }
    else if (i < 262144) { src = Wo;   off = 196608; }
    else if (i < 524288) { src = W1;   off = 262144; }
    else                 { src = W2;   off = 524288; }
    const float4 v = *(const float4*)&src[i - off];
    uint2 o = {packbf(v.x, v.y), packbf(v.z, v.w)};
    *(uint2*)&dst[i] = o;
}

// ---------------- rel-pos MLP -> rel[t][c] fp32 ----------------
__global__ void rel_kernel(const float* __restrict__ relW1, const float* __restrict__ relb1,
                           const float* __restrict__ relW2, const float* __restrict__ relb2,
                           float* __restrict__ rel) {
    __shared__ float hid[64];
    int t = blockIdx.x;                  // 0..255
    int ty = t >> 4, tx = t & 15;
    float cx = tx * (1.0f / 15.0f);
    float cy = ty * (1.0f / 15.0f);
    int c = threadIdx.x;
    if (c < 64) {
        float h = relW1[c * 2 + 0] * cx + relW1[c * 2 + 1] * cy + relb1[c];
        hid[c] = fmaxf(h, 0.0f);
    }
    __syncthreads();
    float acc = relb2[c];
    #pragma unroll
    for (int jj = 0; jj < 64; ++jj) acc = fmaf(hid[jj], relW2[c * 64 + jj], acc);
    rel[t * C_DIM + c] = acc;
}

// ---------------- pe (bf16): coalesced glob read + LDS transpose + rel add ----------------
__global__ __launch_bounds__(256) void pe_kernel(const float* __restrict__ glob,
                                                 const float* __restrict__ rel,
                                                 ushortT* __restrict__ peb) {
    __shared__ float tile[32][129];
    const int y = blockIdx.x;
    const int c0 = blockIdx.y * 32;
    const int i = y >> 4, ty = y & 15;
    const int tid = threadIdx.x;
    const int xl = tid & 127;
    #pragma unroll
    for (int p = 0; p < 16; ++p) {
        const int cl = p * 2 + (tid >> 7);
        tile[cl][xl] = glob[(size_t)(c0 + cl) * 16384 + y * 128 + xl];
    }
    __syncthreads();
    const int cl = tid & 31;
    #pragma unroll
    for (int p = 0; p < 16; ++p) {
        const int x = p * 8 + (tid >> 5);
        const int v = i * 8 + (x >> 4);
        const int t = ty * 16 + (x & 15);
        const float val = tile[cl][x] + rel[t * C_DIM + c0 + cl];
        peb[(size_t)(v * 256 + t) * C_DIM + c0 + cl] = f2b(val);
    }
}

// ---------------- window partition: coalesced read + transpose -> Xb and XPEb ----------------
__global__ __launch_bounds__(256) void window_kernel(const float* __restrict__ backbone,
                                                     const ushortT* __restrict__ peb,
                                                     ushortT* __restrict__ Xb,
                                                     ushortT* __restrict__ XPEb) {
    __shared__ float tile[32][129];
    const int y = blockIdx.x;
    const int c0 = blockIdx.y * 32;
    const int b = blockIdx.z;
    const int i = y >> 4, ty = y & 15;
    const int tid = threadIdx.x;
    const int xl = tid & 127;
    #pragma unroll
    for (int p = 0; p < 16; ++p) {
        const int cl = p * 2 + (tid >> 7);
        tile[cl][xl] = backbone[(size_t)b * 4194304 + (size_t)(c0 + cl) * 16384 + y * 128 + xl];
    }
    __syncthreads();
    const int cl = tid & 31;
    #pragma unroll
    for (int p = 0; p < 16; ++p) {
        const int x = p * 8 + (tid >> 5);
        const int v = i * 8 + (x >> 4);
        const int t = ty * 16 + (x & 15);
        const size_t vt = (size_t)(v * 256 + t);
        const size_t tok = (size_t)b * PETOK + vt;
        const float val = tile[cl][x];
        Xb[tok * C_DIM + c0 + cl] = f2b(val);
        XPEb[tok * C_DIM + c0 + cl] = f2b(val + b2f(peb[vt * C_DIM + c0 + cl]));
    }
}

// ---------------- scatter back + residual: transpose + coalesced write ----------------
__global__ __launch_bounds__(256) void scatter_kernel(const float* __restrict__ backbone,
                                                      const ushortT* __restrict__ X,
                                                      float* __restrict__ out) {
    __shared__ ushortT tile[128][34];
    const int y = blockIdx.x;
    const int c0 = blockIdx.y * 32;
    const int b = blockIdx.z;
    const int i = y >> 4, ty = y & 15;
    const int tid = threadIdx.x;
    const int cl = tid & 31;
    #pragma unroll
    for (int p = 0; p < 16; ++p) {
        const int x = p * 8 + (tid >> 5);
        const int v = i * 8 + (x >> 4);
        const int t = ty * 16 + (x & 15);
        const size_t tok = (size_t)b * PETOK + v * 256 + t;
        tile[x][cl] = X[tok * C_DIM + c0 + cl];
    }
    __syncthreads();
    const int xl = tid & 127;
    #pragma unroll
    for (int p = 0; p < 16; ++p) {
        const int c = c0 + p * 2 + (tid >> 7);
        const size_t gi = (size_t)b * 4194304 + (size_t)c * 16384 + y * 128 + xl;
        out[gi] = backbone[gi] + b2f(tile[xl][p * 2 + (tid >> 7)]);
    }
}

// ---------------- bf16 MFMA GEMM (m97 single-buffer, pure gload_lds) + XCD swizzle ----------
// QKVMODE: A-panel = (n0 < 512) ? A : A2  (QK columns read X+pe, V columns read X).
#define BM 128
#define BN 128
#define BK 32

template<bool QKVMODE, bool RELU>
__global__ __launch_bounds__(256) void gemm_bf16(
        const ushortT* __restrict__ A,
        const ushortT* __restrict__ A2,
        int lda,
        const ushortT* __restrict__ W,
        const float* __restrict__ bias,
        ushortT* __restrict__ Cout, int ldc, int K) {
    __shared__ ushortT As[BM][BK];
    __shared__ ushortT Bs[BN][BK];
    const int nwg = gridDim.x * gridDim.y;
    const int flat = blockIdx.y * gridDim.x + blockIdx.x;
    const int cpx = nwg >> 3;
    const int swz = (flat & 7) * cpx + (flat >> 3);
    const int m0 = (swz / gridDim.x) * BM;
    const int n0 = (swz % gridDim.x) * BN;
    const ushortT* Ause = (QKVMODE && n0 >= 512) ? A2 : A;
    const int tid = threadIdx.x;
    const int lane = tid & 63;
    const int wave = tid >> 6;
    const int wm = (wave >> 1) * 64;
    const int wn = (wave & 1) * 64;
    const int fr = lane & 15;
    const int fg = lane >> 4;
    const int gRow = wave * 32 + (lane >> 2);
    const int gCol = (lane & 3) * 8;

    f32x4 acc[4][4];
    #pragma unroll
    for (int i = 0; i < 4; ++i)
        #pragma unroll
        for (int j = 0; j < 4; ++j)
            acc[i][j] = (f32x4){0.f, 0.f, 0.f, 0.f};

    for (int k0 = 0; k0 < K; k0 += BK) {
        gload_lds16(&Ause[(size_t)(m0 + gRow) * lda + k0 + gCol], &As[wave * 32][0]);
        gload_lds16(&Ause[(size_t)(m0 + gRow + 16) * lda + k0 + gCol], &As[wave * 32 + 16][0]);
        gload_lds16(&W[(size_t)(n0 + gRow) * K + k0 + gCol], &Bs[wave * 32][0]);
        gload_lds16(&W[(size_t)(n0 + gRow + 16) * K + k0 + gCol], &Bs[wave * 32 + 16][0]);
        __syncthreads();
        frag_ab af[4], bf[4];
        #pragma unroll
        for (int i = 0; i < 4; ++i) af[i] = *(const frag_ab*)&As[wm + i * 16 + fr][fg * 8];
        #pragma unroll
        for (int j = 0; j < 4; ++j) bf[j] = *(const frag_ab*)&Bs[wn + j * 16 + fr][fg * 8];
        #pragma unroll
        for (int i = 0; i < 4; ++i)
            #pragma unroll
            for (int j = 0; j < 4; ++j)
                acc[i][j] = __builtin_amdgcn_mfma_f32_16x16x32_bf16(af[i], bf[j], acc[i][j], 0, 0, 0);
        __syncthreads();
    }
    #pragma unroll
    for (int j = 0; j < 4; ++j) {
        const float bv = bias[n0 + wn + j * 16 + fr];
        #pragma unroll
        for (int i = 0; i < 4; ++i) {
            #pragma unroll
            for (int r = 0; r < 4; ++r) {
                float v = acc[i][j][r] + bv;
                if (RELU) v = fmaxf(v, 0.0f);
                const int m = m0 + wm + i * 16 + fg * 4 + r;
                const int n = n0 + wn + j * 16 + fr;
                Cout[(size_t)m * ldc + n] = f2b(v);
            }
        }
    }
}

// ---------------- attn pass 0: 4 waves, flash over 2 KV-chunks of 128 (QKV stride 768) ------
#define KVC 128
__global__ __launch_bounds__(256) void attn_p0(const ushortT* __restrict__ QKVb,
                                               ushortT* __restrict__ Ob) {
    __shared__ ushortT K_lds[KVC * 40];      // 10.0 KB
    __shared__ ushortT V_t[32 * 136];        //  8.5 KB
    __shared__ ushortT P_lds[4][16 * 136];   // 17.0 KB
    const int grp = blockIdx.x;              // (b*64+v)*8 + h
    const int h = grp & 7;
    const int bv = grp >> 3;
    const int base = (bv >> 6) * PETOK + (bv & 63) * 256;
    const int tid = threadIdx.x;
    const int wave = tid >> 6;
    const int lane = tid & 63;
    const int fr = lane & 15;
    const int fg = lane >> 4;
    const float scale = 0.17677669529663687f;   // 1/sqrt(32)

    frag_ab qf[4];
    size_t qtok[4];
    #pragma unroll
    for (int s = 0; s < 4; ++s) {
        qtok[s] = (size_t)(base + wave * 64 + s * 16 + fr);
        qf[s] = *(const frag_ab*)&QKVb[qtok[s] * 768 + h * DH + fg * 8];
    }
    float m[4], l[4];
    f32x4 o0[4], o1[4];
    #pragma unroll
    for (int s = 0; s < 4; ++s) {
        m[s] = -1e30f; l[s] = 0.f;
        o0[s] = (f32x4){0.f, 0.f, 0.f, 0.f};
        o1[s] = (f32x4){0.f, 0.f, 0.f, 0.f};
    }

    for (int c = 0; c < 2; ++c) {
        __syncthreads();
        #pragma unroll
        for (int it = 0; it < 2; ++it) {
            const int idx = it * 256 + tid;  // 0..511
            const int row = idx >> 2, ch = idx & 3;
            const size_t tok = (size_t)(base + c * KVC + row);
            const uint4 kv = *(const uint4*)&QKVb[tok * 768 + 256 + h * DH + ch * 8];
            *(uint4*)&K_lds[row * 40 + ch * 8] = kv;
            const uint4 vv = *(const uint4*)&QKVb[tok * 768 + 512 + h * DH + ch * 8];
            const ushortT* vp = (const ushortT*)&vv;
            #pragma unroll
            for (int e = 0; e < 8; ++e) V_t[(ch * 8 + e) * 136 + row] = vp[e];
        }
        __syncthreads();
        #pragma unroll
        for (int s = 0; s < 4; ++s) {
            f32x4 sc[8];
            #pragma unroll
            for (int kt = 0; kt < 8; ++kt) {
                const frag_ab kf = *(const frag_ab*)&K_lds[(kt * 16 + fr) * 40 + fg * 8];
                sc[kt] = __builtin_amdgcn_mfma_f32_16x16x32_bf16(kf, qf[s], (f32x4){0.f, 0.f, 0.f, 0.f}, 0, 0, 0);
            }
            float mx = -1e30f;
            #pragma unroll
            for (int kt = 0; kt < 8; ++kt)
                mx = fmaxf(mx, fmaxf(fmaxf(sc[kt][0], sc[kt][1]), fmaxf(sc[kt][2], sc[kt][3])));
            mx = fmaxf(mx, __shfl_xor(mx, 16, 64));
            mx = fmaxf(mx, __shfl_xor(mx, 32, 64));
            const float nm = fmaxf(m[s], mx);
            const float corr = __expf((m[s] - nm) * scale);
            m[s] = nm;
            float lsum = 0.f;
            #pragma unroll
            for (int kt = 0; kt < 8; ++kt) {
                const float p0 = __expf((sc[kt][0] - nm) * scale);
                const float p1 = __expf((sc[kt][1] - nm) * scale);
                const float p2 = __expf((sc[kt][2] - nm) * scale);
                const float p3 = __expf((sc[kt][3] - nm) * scale);
                lsum += (p0 + p1) + (p2 + p3);
                uint2 pk;
                pk.x = packbf(p0, p1);
                pk.y = packbf(p2, p3);
                *(uint2*)&P_lds[wave][fr * 136 + kt * 16 + fg * 4] = pk;
            }
            lsum += __shfl_xor(lsum, 16, 64);
            lsum += __shfl_xor(lsum, 32, 64);
            l[s] = l[s] * corr + lsum;
            o0[s] *= corr;
            o1[s] *= corr;
            #pragma unroll
            for (int kc = 0; kc < 4; ++kc) {
                const frag_ab pf = *(const frag_ab*)&P_lds[wave][fr * 136 + kc * 32 + fg * 8];
                const frag_ab v0 = *(const frag_ab*)&V_t[fr * 136 + kc * 32 + fg * 8];
                const frag_ab v1 = *(const frag_ab*)&V_t[(16 + fr) * 136 + kc * 32 + fg * 8];
                o0[s] = __builtin_amdgcn_mfma_f32_16x16x32_bf16(v0, pf, o0[s], 0, 0, 0);
                o1[s] = __builtin_amdgcn_mfma_f32_16x16x32_bf16(v1, pf, o1[s], 0, 0, 0);
            }
        }
    }
    #pragma unroll
    for (int s = 0; s < 4; ++s) {
        const float inv = 1.0f / l[s];
        ushortT* ob = &Ob[qtok[s] * C_DIM + h * DH];
        uint2 w0, w1;
        w0.x = packbf(o0[s][0] * inv, o0[s][1] * inv);
        w0.y = packbf(o0[s][2] * inv, o0[s][3] * inv);
        w1.x = packbf(o1[s][0] * inv, o1[s][1] * inv);
        w1.y = packbf(o1[s][2] * inv, o1[s][3] * inv);
        *(uint2*)&ob[fg * 4] = w0;
        *(uint2*)&ob[16 + fg * 4] = w1;
    }
}

// ---------------- attn pass 1 (S=64): single-shot softmax per wave (QKV stride 768) ---------
__global__ __launch_bounds__(256) void attn_p1(const ushortT* __restrict__ QKVb,
                                               ushortT* __restrict__ Ob) {
    __shared__ ushortT K_lds[4][64 * 40];
    __shared__ ushortT V_t[4][32 * 72];
    __shared__ ushortT P_lds[4][16 * 72];
    const int wave = threadIdx.x >> 6;
    const int lane = threadIdx.x & 63;
    const int unit = blockIdx.x * 4 + wave;
    const int h = unit & 7;
    const int g = unit >> 3;
    const int base = (g >> 8) * PETOK + (g & 255);
    const int fr = lane & 15;
    const int fg = lane >> 4;
    const float scale = 0.17677669529663687f;
    #pragma unroll
    for (int it = 0; it < 4; ++it) {
        const int idx = it * 64 + lane;
        const int row = idx >> 2, ch = idx & 3;
        const size_t tok = (size_t)(base + row * 256);
        const uint4 kv = *(const uint4*)&QKVb[tok * 768 + 256 + h * DH + ch * 8];
        *(uint4*)&K_lds[wave][row * 40 + ch * 8] = kv;
        const uint4 vv = *(const uint4*)&QKVb[tok * 768 + 512 + h * DH + ch * 8];
        const ushortT* vp = (const ushortT*)&vv;
        #pragma unroll
        for (int e = 0; e < 8; ++e) V_t[wave][(ch * 8 + e) * 72 + row] = vp[e];
    }
    #pragma unroll
    for (int s = 0; s < 4; ++s) {
        const int qq = s * 16 + fr;
        const size_t qtok = (size_t)(base + qq * 256);
        const frag_ab qf = *(const frag_ab*)&QKVb[qtok * 768 + h * DH + fg * 8];
        f32x4 sc[4];
        #pragma unroll
        for (int kt = 0; kt < 4; ++kt) {
            const frag_ab kf = *(const frag_ab*)&K_lds[wave][(kt * 16 + fr) * 40 + fg * 8];
            sc[kt] = __builtin_amdgcn_mfma_f32_16x16x32_bf16(kf, qf, (f32x4){0.f, 0.f, 0.f, 0.f}, 0, 0, 0);
        }
        float mx = -1e30f;
        #pragma unroll
        for (int kt = 0; kt < 4; ++kt)
            mx = fmaxf(mx, fmaxf(fmaxf(sc[kt][0], sc[kt][1]), fmaxf(sc[kt][2], sc[kt][3])));
        mx = fmaxf(mx, __shfl_xor(mx, 16, 64));
        mx = fmaxf(mx, __shfl_xor(mx, 32, 64));
        float lsum = 0.f;
        #pragma unroll
        for (int kt = 0; kt < 4; ++kt) {
            const float p0 = __expf((sc[kt][0] - mx) * scale);
            const float p1 = __expf((sc[kt][1] - mx) * scale);
            const float p2 = __expf((sc[kt][2] - mx) * scale);
            const float p3 = __expf((sc[kt][3] - mx) * scale);
            lsum += (p0 + p1) + (p2 + p3);
            uint2 pk;
            pk.x = packbf(p0, p1);
            pk.y = packbf(p2, p3);
            *(uint2*)&P_lds[wave][fr * 72 + kt * 16 + fg * 4] = pk;
        }
        lsum += __shfl_xor(lsum, 16, 64);
        lsum += __shfl_xor(lsum, 32, 64);
        f32x4 o0 = {0.f, 0.f, 0.f, 0.f}, o1 = {0.f, 0.f, 0.f, 0.f};
        #pragma unroll
        for (int kc = 0; kc < 2; ++kc) {
            const frag_ab pf = *(const frag_ab*)&P_lds[wave][fr * 72 + kc * 32 + fg * 8];
            const frag_ab v0 = *(const frag_ab*)&V_t[wave][fr * 72 + kc * 32 + fg * 8];
            const frag_ab v1 = *(const frag_ab*)&V_t[wave][(16 + fr) * 72 + kc * 32 + fg * 8];
            o0 = __builtin_amdgcn_mfma_f32_16x16x32_bf16(v0, pf, o0, 0, 0, 0);
            o1 = __builtin_amdgcn_mfma_f32_16x16x32_bf16(v1, pf, o1, 0, 0, 0);
        }
        const float inv = 1.0f / lsum;
        ushortT* ob = &Ob[qtok * C_DIM + h * DH];
        uint2 w0, w1;
        w0.x = packbf(o0[0] * inv, o0[1] * inv);
        w0.y = packbf(o0[2] * inv, o0[3] * inv);
        w1.x = packbf(o1[0] * inv, o1[1] * inv);
        w1.y = packbf(o1[2] * inv, o1[3] * inv);
        *(uint2*)&ob[fg * 4] = w0;
        *(uint2*)&ob[16 + fg * 4] = w1;
    }
}

// ---------------- residual + LayerNorm (bf16 stream), optional XPE output -------------------
template<bool WXPE>
__global__ __launch_bounds__(256) void ln_kernel(ushortT* __restrict__ X, const ushortT* __restrict__ Y,
                                                 const float* __restrict__ g, const float* __restrict__ be,
                                                 const ushortT* __restrict__ peb,
                                                 ushortT* __restrict__ XPE) {
    int tok = blockIdx.x * 4 + (threadIdx.x >> 6);
    int lane = threadIdx.x & 63;
    const uint2 xu = *(const uint2*)&X[(size_t)tok * C_DIM + lane * 4];
    const uint2 yu = *(const uint2*)&Y[(size_t)tok * C_DIM + lane * 4];
    float v0 = bflo(xu.x) + bflo(yu.x), v1 = bfhi(xu.x) + bfhi(yu.x);
    float v2 = bflo(xu.y) + bflo(yu.y), v3 = bfhi(xu.y) + bfhi(yu.y);
    float s = v0 + v1 + v2 + v3;
    float ss = v0 * v0 + v1 * v1 + v2 * v2 + v3 * v3;
    #pragma unroll
    for (int off = 32; off; off >>= 1) {
        s += __shfl_xor(s, off, 64);
        ss += __shfl_xor(ss, off, 64);
    }
    float mean = s * (1.0f / 256.0f);
    float var = ss * (1.0f / 256.0f) - mean * mean;
    float inv = rsqrtf(var + LN_EPS);
    const float4 gv = *(const float4*)&g[lane * 4];
    const float4 bv = *(const float4*)&be[lane * 4];
    float o0 = (v0 - mean) * inv * gv.x + bv.x;
    float o1 = (v1 - mean) * inv * gv.y + bv.y;
    float o2 = (v2 - mean) * inv * gv.z + bv.z;
    float o3 = (v3 - mean) * inv * gv.w + bv.w;
    uint2 ob = {packbf(o0, o1), packbf(o2, o3)};
    *(uint2*)&X[(size_t)tok * C_DIM + lane * 4] = ob;
    if (WXPE) {
        const size_t vt = (size_t)(tok & 16383);
        const uint2 pu = *(const uint2*)&peb[vt * C_DIM + lane * 4];
        uint2 xp;
        xp.x = packbf(o0 + bflo(pu.x), o1 + bfhi(pu.x));
        xp.y = packbf(o2 + bflo(pu.y), o3 + bfhi(pu.y));
        *(uint2*)&XPE[(size_t)tok * C_DIM + lane * 4] = xp;
    }
}

// ---------------- defe mask: parallel maxpool ----------------
__global__ void mask_kernel(const float* __restrict__ defe, float* __restrict__ out) {
    __shared__ float wmax[4];
    const int idx = blockIdx.x;          // 0..127
    const int b = idx >> 6;
    const int ii = (idx >> 3) & 7;
    const int jj = idx & 7;
    const int t = threadIdx.x;
    const int y = t >> 4, xx = t & 15;
    float v = defe[b * 16384 + (ii * 16 + y) * 128 + jj * 16 + xx];
    #pragma unroll
    for (int off = 32; off; off >>= 1) v = fmaxf(v, __shfl_xor(v, off, 64));
    if ((t & 63) == 0) wmax[t >> 6] = v;
    __syncthreads();
    if (t == 0) {
        float mx = fmaxf(fmaxf(wmax[0], wmax[1]), fmaxf(wmax[2], wmax[3]));
        out[8388608 + idx] = (mx > 0.0f) ? 1.0f : 0.0f;
    }
}

extern "C" void kernel_launch(void* const* d_in, const int* in_sizes, int n_in,
                              void* d_out, int out_size, void* d_ws, size_t ws_size,
                              hipStream_t stream) {
    const float* backbone = (const float*)d_in[0];
    const float* defe     = (const float*)d_in[1];
    const float* glob     = (const float*)d_in[2];
    const float* Wqkv     = (const float*)d_in[3];
    const float* bqkv     = (const float*)d_in[4];
    const float* Wo       = (const float*)d_in[5];
    const float* bo       = (const float*)d_in[6];
    const float* W1       = (const float*)d_in[7];
    const float* b1       = (const float*)d_in[8];
    const float* W2       = (const float*)d_in[9];
    const float* b2       = (const float*)d_in[10];
    const float* g1       = (const float*)d_in[11];
    const float* be1      = (const float*)d_in[12];
    const float* g2       = (const float*)d_in[13];
    const float* be2      = (const float*)d_in[14];
    const float* relW1    = (const float*)d_in[15];
    const float* relb1    = (const float*)d_in[16];
    const float* relW2    = (const float*)d_in[17];
    const float* relb2    = (const float*)d_in[18];

    // workspace layout (ushorts)
    ushortT* peb    = (ushortT*)d_ws;                       //  4,194,304
    ushortT* Wqkv_b = peb + 4194304;                        //    196,608
    ushortT* Wo_b   = Wqkv_b + 196608;                      //     65,536
    ushortT* W1_b   = Wo_b + 65536;                         //    262,144
    ushortT* W2_b   = W1_b + 262144;                        //    262,144
    ushortT* Xb     = W2_b + 262144;                        //  8,388,608
    ushortT* XPEb   = Xb + 8388608;                         //  8,388,608 (X + pe, bf16)
    ushortT* QKVb   = XPEb + 8388608;                       // 25,165,824 (Q|K|V, stride 768)
    ushortT* Ob     = QKVb + 25165824;                      //  8,388,608 (contiguous after QKVb)
    ushortT* Hb     = QKVb;                                 // FFN hidden aliases QKV|O (33.5M)
    ushortT* Yb     = Ob + 8388608;                         //  8,388,608
    float*   relf   = (float*)(Yb + 8388608);               //     65,536 floats
    size_t needed = (size_t)((char*)(relf + 65536) - (char*)d_ws);
    if (ws_size < needed) return;

    cvt_all_kernel<<<768, 256, 0, stream>>>(Wqkv, Wo, W1, W2, Wqkv_b);
    rel_kernel<<<256, 256, 0, stream>>>(relW1, relb1, relW2, relb2, relf);
    pe_kernel<<<dim3(128, 8), 256, 0, stream>>>(glob, relf, peb);
    window_kernel<<<dim3(128, 8, 2), 256, 0, stream>>>(backbone, peb, Xb, XPEb);

    for (int pass = 0; pass < 2; ++pass) {
        // fused QKV: [32768 x 768]; QK columns use XPEb, V columns use Xb
        gemm_bf16<true, false><<<dim3(768 / BN, NTOK / BM), 256, 0, stream>>>(
            XPEb, Xb, C_DIM, Wqkv_b, bqkv, QKVb, 768, C_DIM);
        if (pass == 0) {
            attn_p0<<<128 * NHEAD, 256, 0, stream>>>(QKVb, Ob);
        } else {
            attn_p1<<<4096 / 4, 256, 0, stream>>>(QKVb, Ob);
        }
        gemm_bf16<false, false><<<dim3(256 / BN, NTOK / BM), 256, 0, stream>>>(
            Ob, nullptr, C_DIM, Wo_b, bo, Yb, C_DIM, C_DIM);
        ln_kernel<false><<<NTOK / 4, 256, 0, stream>>>(Xb, Yb, g1, be1, nullptr, nullptr);
        gemm_bf16<false, true><<<dim3(DFF_DIM / BN, NTOK / BM), 256, 0, stream>>>(
            Xb, nullptr, C_DIM, W1_b, b1, Hb, DFF_DIM, C_DIM);
        gemm_bf16<false, false><<<dim3(256 / BN, NTOK / BM), 256, 0, stream>>>(
            Hb, nullptr, DFF_DIM, W2_b, b2, Yb, C_DIM, DFF_DIM);
        if (pass == 0) {
            ln_kernel<true><<<NTOK / 4, 256, 0, stream>>>(Xb, Yb, g2, be2, peb, XPEb);
        } else {
            ln_kernel<false><<<NTOK / 4, 256, 0, stream>>>(Xb, Yb, g2, be2, nullptr, nullptr);
        }
    }

    scatter_kernel<<<dim3(128, 8, 2), 256, 0, stream>>>(backbone, Xb, (float*)d_out);
    mask_kernel<<<128, 256, 0, stream>>>(defe, (float*)d_out);
}